// Round 6
// baseline (230.666 us; speedup 1.0000x reference)
//
#include <hip/hip_runtime.h>
#include <hip/hip_bf16.h>
#include <math.h>

// AttentionLayer: B=16, T=2048, D=256
// out[b,d,s] = h[b,s,d] + sum_t h[b,t,d] * softmax_s(m[b,t,:] @ aw[b,:,:]^T)[s]
//   h = in[...,0:256] + in[...,256:512]; m = tanh(h); aw = relu(h @ W^T + b)
// Pipeline (fp16 intermediates):
//   kA: prep -> h16 [t][d], m16 [t][d], hfrag (MFMA-B-fragment tiled h^T)
//   kB: aw GEMM (W staged fp32->fp16 in LDS)
//   k2s: S = m @ aw^T -> Sfrag; lse; PHASE2: in-place P = exp(S - lse) (exp done ONCE here)
//   k3o: pure GEMM: load P-frag + h-frag -> MFMA PV, residual epilogue. No exp, no LDS.
// Frag layouts:
//   Pfrag[b][s/16][t/32][lane][8]: value(s,t) at lane=(s&15)+16*((t&31)>>3), j=t&7
//   hfrag[b][d/16][t/32][lane][8]: value(d,t) same mapping with d in place of s
// h16 aliases the first 16MB of the Sfrag region (dead after kB, overwritten by k2s).

#define NB 16
#define NT 2048
#define ND 256

typedef __attribute__((ext_vector_type(4))) float f32x4;
typedef __attribute__((ext_vector_type(8))) short s16x8;
typedef __attribute__((ext_vector_type(4))) short s16x4;
typedef __attribute__((ext_vector_type(8))) _Float16 f16x8;
typedef unsigned short u16;

__device__ __forceinline__ u16 f2h(float x) {
  union { _Float16 h; u16 u; } v; v.h = (_Float16)x; return v.u;
}
__device__ __forceinline__ float h2f(u16 u) {
  union { u16 u; _Float16 h; } v; v.u = u; return (float)v.h;
}
__device__ __forceinline__ float tanh_fast(float x) {
  return 1.f - 2.f / (1.f + __expf(2.f * x));  // exact at tails, branch-free
}

// ---------------- kA: h = a+b; h16 [t][d], m16 [t][d], hfrag [d/16][t/32][lane][8] ----------------
__global__ __launch_bounds__(256, 4) void kA(const float* __restrict__ inF,
    u16* __restrict__ h16, u16* __restrict__ m16, u16* __restrict__ hfrag)
{
  __shared__ __attribute__((aligned(16))) u16 hld[64][264];   // [t][d] fp16 h
  const int blk = blockIdx.x;
  const int b   = blk >> 5;
  const int t0  = (blk & 31) << 6;
  const int tid = threadIdx.x;
  const int tloc = tid >> 2;          // 0..63
  const int dseg = (tid & 3) << 6;    // 0/64/128/192
  const float* base = inF + ((size_t)(b * NT + t0 + tloc)) * (2 * ND);
  const size_t rowo = ((size_t)(b * NT + t0 + tloc)) * ND + dseg;
  #pragma unroll
  for (int j0 = 0; j0 < 64; j0 += 8) {
    const int dd = dseg + j0;
    float4 a0 = *(const float4*)(base + dd);
    float4 a1 = *(const float4*)(base + dd + 4);
    float4 c0 = *(const float4*)(base + ND + dd);
    float4 c1 = *(const float4*)(base + ND + dd + 4);
    float hv[8] = {a0.x + c0.x, a0.y + c0.y, a0.z + c0.z, a0.w + c0.w,
                   a1.x + c1.x, a1.y + c1.y, a1.z + c1.z, a1.w + c1.w};
    s16x8 vh, vm;
    #pragma unroll
    for (int r = 0; r < 8; ++r) {
      vh[r] = (short)f2h(hv[r]);
      vm[r] = (short)f2h(tanh_fast(hv[r]));
    }
    *(s16x8*)&hld[tloc][dd] = vh;
    *(s16x8*)(h16 + rowo + j0) = vh;
    *(s16x8*)(m16 + rowo + j0) = vm;
  }
  __syncthreads();
  // phase B: hfrag slots. 2048 slots of 16B; thread handles 8 consecutive.
  u16* Hb = hfrag + (size_t)b * ND * NT;
  const int slot0 = tid * 8;
  #pragma unroll
  for (int rep = 0; rep < 8; ++rep) {
    const int slot = slot0 + rep;
    const int fi = slot >> 6;          // 0..31 (dtile*2 + ttile)
    const int lp = slot & 63;
    const int dtile = fi >> 1, ttile = fi & 1;
    const int d  = dtile * 16 + (lp & 15);
    const int tb = ttile * 32 + (lp >> 4) * 8;
    s16x8 v;
    #pragma unroll
    for (int j = 0; j < 8; ++j) v[j] = (short)hld[tb + j][d];
    *(s16x8*)(Hb + (((size_t)dtile * (NT / 32) + (t0 >> 5) + ttile) * 64 + lp) * 8) = v;
  }
}

// ---------------- kB: aw = relu(h @ W^T + b), fp16, W half staged in LDS ----------------
__global__ __launch_bounds__(256, 2) void kB(const u16* __restrict__ h16,
    const float* __restrict__ W, const float* __restrict__ bias, u16* __restrict__ aw16)
{
  __shared__ __attribute__((aligned(16))) u16 Wl[128][264];
  const int r0 = blockIdx.x << 7;
  const int e0 = blockIdx.y << 7;
  const int tid = threadIdx.x;
  #pragma unroll
  for (int rep = 0; rep < 16; ++rep) {
    const int idx = rep * 2048 + tid * 8;
    const int er = idx >> 8, col = idx & 255;
    float4 x0 = *(const float4*)(W + (size_t)(e0 + er) * ND + col);
    float4 x1 = *(const float4*)(W + (size_t)(e0 + er) * ND + col + 4);
    s16x8 v;
    v[0] = (short)f2h(x0.x); v[1] = (short)f2h(x0.y); v[2] = (short)f2h(x0.z); v[3] = (short)f2h(x0.w);
    v[4] = (short)f2h(x1.x); v[5] = (short)f2h(x1.y); v[6] = (short)f2h(x1.z); v[7] = (short)f2h(x1.w);
    *(s16x8*)&Wl[er][col] = v;
  }
  const int lane = tid & 63;
  const int w    = tid >> 6;
  const int l15  = lane & 15, kg = lane >> 4;
  float bv[8];
  #pragma unroll
  for (int et = 0; et < 8; ++et) bv[et] = bias[e0 + et * 16 + l15];
  f32x4 acc[2][8];
  #pragma unroll
  for (int rt = 0; rt < 2; ++rt)
    #pragma unroll
    for (int et = 0; et < 8; ++et) acc[rt][et] = (f32x4){0.f, 0.f, 0.f, 0.f};
  __syncthreads();
  #pragma unroll
  for (int ks = 0; ks < 8; ++ks) {
    f16x8 af[2];
    #pragma unroll
    for (int rt = 0; rt < 2; ++rt)
      af[rt] = *(const f16x8*)(h16 + (size_t)(r0 + w * 32 + rt * 16 + l15) * ND + ks * 32 + kg * 8);
    #pragma unroll
    for (int et = 0; et < 8; ++et) {
      f16x8 bf = *(const f16x8*)&Wl[et * 16 + l15][ks * 32 + kg * 8];
      #pragma unroll
      for (int rt = 0; rt < 2; ++rt)
        acc[rt][et] = __builtin_amdgcn_mfma_f32_16x16x32_f16(af[rt], bf, acc[rt][et], 0, 0, 0);
    }
  }
  #pragma unroll
  for (int rt = 0; rt < 2; ++rt)
    #pragma unroll
    for (int et = 0; et < 8; ++et) {
      const int e = e0 + et * 16 + l15;
      #pragma unroll
      for (int r = 0; r < 4; ++r) {
        const int row = r0 + w * 32 + rt * 16 + kg * 4 + r;
        float v = acc[rt][et][r] + bv[et];
        aw16[(size_t)row * ND + e] = f2h(v > 0.f ? v : 0.f);
      }
    }
}

// ---------------- k2s: Sfrag + lse; phase 2: in-place P = exp(S - lse) ----------------
__global__ __launch_bounds__(256, 2) void k2s(
    const u16* __restrict__ m16, const u16* __restrict__ aw16,
    u16* __restrict__ Sfrag, float* __restrict__ lse)
{
  __shared__ __attribute__((aligned(16))) u16 awch[2][64][264];
  __shared__ float lse_s[64];
  const int blk = blockIdx.x;
  const int b   = blk >> 5;
  const int t0  = (blk & 31) << 6;
  const int tid = threadIdx.x;
  const int lane = tid & 63;
  const int w    = tid >> 6;
  const int l15 = lane & 15, kg = lane >> 4;
  f16x8 afr[8];
  const size_t abase = ((size_t)(b * NT + t0 + w * 16 + l15)) * ND + kg * 8;
  #pragma unroll
  for (int ks = 0; ks < 8; ++ks) afr[ks] = *(const f16x8*)(m16 + abase + ks * 32);
  const u16* awb = aw16 + (size_t)b * NT * ND;
  u16* STb = Sfrag + (size_t)b * NT * NT;
  // frag-store constants for this thread
  const int ti0   = t0 >> 5;
  const int ti    = ti0 + (w >> 1);
  const int lanep = l15 + 16 * ((w & 1) * 2 + (kg >> 1));
  const int jp    = (kg & 1) * 4;
  auto stage = [&](int ch, int buf) {
    const int s0 = ch << 6;
    #pragma unroll
    for (int rep = 0; rep < 8; ++rep) {
      const int idx = rep * 2048 + tid * 8;
      const int srow = idx >> 8, col = idx & 255;
      *(s16x8*)&awch[buf][srow][col] = *(const s16x8*)(awb + (size_t)(s0 + srow) * ND + col);
    }
  };
  stage(0, 0);
  float zacc[4] = {0.f, 0.f, 0.f, 0.f};
  __syncthreads();
  for (int ch = 0; ch < 32; ++ch) {
    const int c = ch & 1;
    if (ch < 31) stage(ch + 1, c ^ 1);
    f32x4 accS[4];
    #pragma unroll
    for (int st = 0; st < 4; ++st) accS[st] = (f32x4){0.f, 0.f, 0.f, 0.f};
    #pragma unroll
    for (int ks = 0; ks < 8; ++ks) {
      #pragma unroll
      for (int st = 0; st < 4; ++st) {
        f16x8 bf = *(const f16x8*)&awch[c][st * 16 + l15][ks * 32 + kg * 8];
        accS[st] = __builtin_amdgcn_mfma_f32_16x16x32_f16(afr[ks], bf, accS[st], 0, 0, 0);
      }
    }
    // frag-layout S store (coalesced) + Z accumulate
    #pragma unroll
    for (int st = 0; st < 4; ++st) {
      const int si = ch * 4 + st;
      s16x4 sv;
      #pragma unroll
      for (int r = 0; r < 4; ++r) sv[r] = (short)f2h(accS[st][r]);
      *(s16x4*)(STb + (((size_t)si * 64 + ti) * 64 + lanep) * 8 + jp) = sv;
      #pragma unroll
      for (int r = 0; r < 4; ++r) zacc[r] += __expf(accS[st][r]);
    }
    __syncthreads();
  }
  #pragma unroll
  for (int r = 0; r < 4; ++r) {
    #pragma unroll
    for (int o = 1; o < 16; o <<= 1) zacc[r] += __shfl_xor(zacc[r], o, 64);
  }
  if (l15 == 0) {
    #pragma unroll
    for (int r = 0; r < 4; ++r) {
      const float v = __logf(zacc[r]);
      lse[(size_t)b * NT + t0 + w * 16 + kg * 4 + r] = v;
      lse_s[w * 16 + kg * 4 + r] = v;
    }
  }
  __syncthreads();   // lse_s ready; phase-1 global S stores drained (vmcnt0 at barrier)
  // ---- phase 2: P = exp(S - lse) in-place over this block's S region (L2-hot) ----
  // block region: 128 si x 2 ttiles x 64 lanes slots of 16B = 256 KB
  for (int rep = 0; rep < 64; ++rep) {
    const int L   = rep * 256 + tid;       // slot index within block region
    const int ln  = L & 63;
    const int tto = (L >> 6) & 1;
    const int si  = L >> 7;
    u16* slot = STb + (((size_t)si * 64 + ti0 + tto) * 64 + ln) * 8;
    s16x8 v = *(const s16x8*)slot;
    const int tloc = tto * 32 + (ln >> 4) * 8;
    float4 La = *(const float4*)&lse_s[tloc];
    float4 Lb = *(const float4*)&lse_s[tloc + 4];
    const float nl[8] = {La.x, La.y, La.z, La.w, Lb.x, Lb.y, Lb.z, Lb.w};
    s16x8 p;
    #pragma unroll
    for (int j = 0; j < 8; ++j) p[j] = (short)f2h(__expf(h2f((u16)v[j]) - nl[j]));
    *(s16x8*)slot = p;
  }
}

// ---------------- k3o: pure GEMM. O[s,d] = sum_t P[s,t] h[d,t]; out = h^T + O^T ----------------
__global__ __launch_bounds__(256, 2) void k3o(
    const u16* __restrict__ Pfrag, const u16* __restrict__ hfrag,
    float* __restrict__ outp)
{
  const int b   = blockIdx.y;
  const int s0t = blockIdx.x;          // s-tile of 64 (0..31)
  const int tid = threadIdx.x;
  const int lane = tid & 63;
  const int w    = tid >> 6;           // wave owns d-slice [w*64, +64)
  const int l15 = lane & 15, kg = lane >> 4;
  const u16* Pb = Pfrag + (size_t)b * NT * NT;
  const u16* Hb = hfrag + (size_t)b * ND * NT;

  f32x4 acc[4][4];
  #pragma unroll
  for (int st = 0; st < 4; ++st)
    #pragma unroll
    for (int dt = 0; dt < 4; ++dt) acc[st][dt] = (f32x4){0.f, 0.f, 0.f, 0.f};

  const u16* sp[4];
  #pragma unroll
  for (int st = 0; st < 4; ++st)
    sp[st] = Pb + (((size_t)(s0t * 4 + st) * 64) * 64 + lane) * 8;
  const u16* hp[4];
  #pragma unroll
  for (int dt = 0; dt < 4; ++dt)
    hp[dt] = Hb + (((size_t)(w * 4 + dt) * 64) * 64 + lane) * 8;

  f16x8 pA[4][2], pB[4][2];

  auto loadP = [&](f16x8 (&dst)[4][2], int ch) {
    #pragma unroll
    for (int st = 0; st < 4; ++st)
      #pragma unroll
      for (int ks = 0; ks < 2; ++ks)
        dst[st][ks] = *(const f16x8*)(sp[st] + (size_t)(ch * 2 + ks) * 512);
  };

  auto compute = [&](f16x8 (&P)[4][2], int ch) {
    f16x8 hb[4][2];
    #pragma unroll
    for (int dt = 0; dt < 4; ++dt)
      #pragma unroll
      for (int ks = 0; ks < 2; ++ks)
        hb[dt][ks] = *(const f16x8*)(hp[dt] + (size_t)(ch * 2 + ks) * 512);
    #pragma unroll
    for (int ks = 0; ks < 2; ++ks)
      #pragma unroll
      for (int dt = 0; dt < 4; ++dt)
        #pragma unroll
        for (int st = 0; st < 4; ++st)
          acc[st][dt] = __builtin_amdgcn_mfma_f32_16x16x32_f16(P[st][ks], hb[dt][ks], acc[st][dt], 0, 0, 0);
  };

  loadP(pA, 0);
  for (int ch = 0; ch < 32; ch += 2) {
    loadP(pB, ch + 1);
    compute(pA, ch);
    if (ch + 2 < 32) loadP(pA, ch + 2);
    compute(pB, ch + 1);
  }
  // epilogue: out[b][d][s] = h[d][s] + O[s][d]; residual h from hfrag
  #pragma unroll
  for (int st = 0; st < 4; ++st) {
    const int sb = s0t * 64 + st * 16 + kg * 4;
    #pragma unroll
    for (int dt = 0; dt < 4; ++dt) {
      const int d = w * 64 + dt * 16 + l15;
      const u16* hres = Hb + (((size_t)(w * 4 + dt) * 64 + (s0t * 2 + (st >> 1))) * 64
                        + (l15 + 16 * ((st & 1) * 2 + (kg >> 1)))) * 8 + (kg & 1) * 4;
      float4 o;
      o.x = acc[st][dt][0] + h2f(hres[0]);
      o.y = acc[st][dt][1] + h2f(hres[1]);
      o.z = acc[st][dt][2] + h2f(hres[2]);
      o.w = acc[st][dt][3] + h2f(hres[3]);
      *(float4*)(outp + ((size_t)(b * ND + d)) * NT + sb) = o;
    }
  }
}

extern "C" void kernel_launch(void* const* d_in, const int* in_sizes, int n_in,
                              void* d_out, int out_size, void* d_ws, size_t ws_size,
                              hipStream_t stream) {
  const float* inF  = (const float*)d_in[0];  // [16][2048][512]
  const float* W    = (const float*)d_in[1];  // [256][256]
  const float* bias = (const float*)d_in[2];  // [256]
  float* outp = (float*)d_out;                // [16][256][2048]

  const size_t SZ = (size_t)NB * NT * ND;     // 8,388,608 elems
  u16* m16   = (u16*)d_ws;
  u16* hfrag = m16 + SZ;
  u16* aw16  = hfrag + SZ;
  float* lse = (float*)(aw16 + SZ);
  u16* Sfrag = (u16*)(lse + (size_t)NB * NT); // fp16 fragment-tiled S^T -> P, 128 MiB
  u16* h16   = Sfrag;                          // alias: dead after kB, overwritten by k2s
  const size_t need = 3 * SZ * sizeof(u16) + (size_t)NB * NT * sizeof(float)
                    + (size_t)NB * NT * NT * sizeof(u16);   // ~176.2 MB (proven present)
  if (ws_size < need) return;  // visible failure (output stays poisoned)

  kA <<<dim3(NB * NT / 64), dim3(256), 0, stream>>>(inF, h16, m16, hfrag);
  kB <<<dim3(256, 2), dim3(256), 0, stream>>>(h16, W, bias, aw16);
  k2s<<<dim3(NB * NT / 64), dim3(256), 0, stream>>>(m16, aw16, Sfrag, lse);
  k3o<<<dim3(NT / 64, NB), dim3(256), 0, stream>>>(Sfrag, hfrag, outp);
}

// Round 7
// 182.764 us; speedup vs baseline: 1.2621x; 1.2621x over previous
//
#include <hip/hip_runtime.h>
#include <hip/hip_bf16.h>
#include <math.h>

// AttentionLayer: B=16, T=2048, D=256
// out[b,d,s] = h[b,s,d] + sum_t h[b,t,d] * softmax_s(m[b,t,:] @ aw[b,:,:]^T)[s]
//   h = in[...,0:256] + in[...,256:512]; m = tanh(h); aw = relu(h @ W^T + b)
// Pipeline (fp16 intermediates):
//   kA: prep -> h16 [t][d], m16 [t][d], hfrag (MFMA-B-fragment tiled h^T)
//   kB: aw GEMM (W staged fp32->fp16 in LDS)
//   k2z: S = m @ aw^T -> Sfrag (raw S, frag-tiled) + Z[b][t] = sum_s exp(S). 8 waves,
//        even/odd s-subchunk split across wave groups, partial-Z LDS combine. 16 waves/CU.
//   k3o: cooperative exp: each of 8 waves loads its own S sub-frag, P=exp(S)/Z -> LDS,
//        all waves MFMA PV from LDS. 1 barrier/chunk, S prefetch depth 2. 16 waves/CU.
// Frag layouts:
//   Sfrag[b][s/16][t/32][lane][8]: value(s,t) at lane=(s&15)+16*((t&31)>>3), j=t&7
//   hfrag[b][d/16][t/32][lane][8]: value(d,t) same mapping with d in place of s
// h16 aliases the first 16MB of the Sfrag region (dead after kB, overwritten by k2z).

#define NB 16
#define NT 2048
#define ND 256

typedef __attribute__((ext_vector_type(4))) float f32x4;
typedef __attribute__((ext_vector_type(8))) short s16x8;
typedef __attribute__((ext_vector_type(4))) short s16x4;
typedef __attribute__((ext_vector_type(8))) _Float16 f16x8;
typedef unsigned short u16;

__device__ __forceinline__ u16 f2h(float x) {
  union { _Float16 h; u16 u; } v; v.h = (_Float16)x; return v.u;
}
__device__ __forceinline__ float h2f(u16 u) {
  union { u16 u; _Float16 h; } v; v.u = u; return (float)v.h;
}
__device__ __forceinline__ float tanh_fast(float x) {
  return 1.f - 2.f / (1.f + __expf(2.f * x));  // exact at tails, branch-free
}

// ---------------- kA: h = a+b; h16 [t][d], m16 [t][d], hfrag [d/16][t/32][lane][8] ----------------
__global__ __launch_bounds__(256, 4) void kA(const float* __restrict__ inF,
    u16* __restrict__ h16, u16* __restrict__ m16, u16* __restrict__ hfrag)
{
  __shared__ __attribute__((aligned(16))) u16 hld[64][264];   // [t][d] fp16 h
  const int blk = blockIdx.x;
  const int b   = blk >> 5;
  const int t0  = (blk & 31) << 6;
  const int tid = threadIdx.x;
  const int tloc = tid >> 2;          // 0..63
  const int dseg = (tid & 3) << 6;    // 0/64/128/192
  const float* base = inF + ((size_t)(b * NT + t0 + tloc)) * (2 * ND);
  const size_t rowo = ((size_t)(b * NT + t0 + tloc)) * ND + dseg;
  #pragma unroll
  for (int j0 = 0; j0 < 64; j0 += 8) {
    const int dd = dseg + j0;
    float4 a0 = *(const float4*)(base + dd);
    float4 a1 = *(const float4*)(base + dd + 4);
    float4 c0 = *(const float4*)(base + ND + dd);
    float4 c1 = *(const float4*)(base + ND + dd + 4);
    float hv[8] = {a0.x + c0.x, a0.y + c0.y, a0.z + c0.z, a0.w + c0.w,
                   a1.x + c1.x, a1.y + c1.y, a1.z + c1.z, a1.w + c1.w};
    s16x8 vh, vm;
    #pragma unroll
    for (int r = 0; r < 8; ++r) {
      vh[r] = (short)f2h(hv[r]);
      vm[r] = (short)f2h(tanh_fast(hv[r]));
    }
    *(s16x8*)&hld[tloc][dd] = vh;
    *(s16x8*)(h16 + rowo + j0) = vh;
    *(s16x8*)(m16 + rowo + j0) = vm;
  }
  __syncthreads();
  // phase B: hfrag slots. 2048 slots of 16B; thread handles 8 consecutive.
  u16* Hb = hfrag + (size_t)b * ND * NT;
  const int slot0 = tid * 8;
  #pragma unroll
  for (int rep = 0; rep < 8; ++rep) {
    const int slot = slot0 + rep;
    const int fi = slot >> 6;          // 0..31 (dtile*2 + ttile)
    const int lp = slot & 63;
    const int dtile = fi >> 1, ttile = fi & 1;
    const int d  = dtile * 16 + (lp & 15);
    const int tb = ttile * 32 + (lp >> 4) * 8;
    s16x8 v;
    #pragma unroll
    for (int j = 0; j < 8; ++j) v[j] = (short)hld[tb + j][d];
    *(s16x8*)(Hb + (((size_t)dtile * (NT / 32) + (t0 >> 5) + ttile) * 64 + lp) * 8) = v;
  }
}

// ---------------- kB: aw = relu(h @ W^T + b), fp16, W half staged in LDS ----------------
__global__ __launch_bounds__(256, 2) void kB(const u16* __restrict__ h16,
    const float* __restrict__ W, const float* __restrict__ bias, u16* __restrict__ aw16)
{
  __shared__ __attribute__((aligned(16))) u16 Wl[128][264];
  const int r0 = blockIdx.x << 7;
  const int e0 = blockIdx.y << 7;
  const int tid = threadIdx.x;
  #pragma unroll
  for (int rep = 0; rep < 16; ++rep) {
    const int idx = rep * 2048 + tid * 8;
    const int er = idx >> 8, col = idx & 255;
    float4 x0 = *(const float4*)(W + (size_t)(e0 + er) * ND + col);
    float4 x1 = *(const float4*)(W + (size_t)(e0 + er) * ND + col + 4);
    s16x8 v;
    v[0] = (short)f2h(x0.x); v[1] = (short)f2h(x0.y); v[2] = (short)f2h(x0.z); v[3] = (short)f2h(x0.w);
    v[4] = (short)f2h(x1.x); v[5] = (short)f2h(x1.y); v[6] = (short)f2h(x1.z); v[7] = (short)f2h(x1.w);
    *(s16x8*)&Wl[er][col] = v;
  }
  const int lane = tid & 63;
  const int w    = tid >> 6;
  const int l15  = lane & 15, kg = lane >> 4;
  float bv[8];
  #pragma unroll
  for (int et = 0; et < 8; ++et) bv[et] = bias[e0 + et * 16 + l15];
  f32x4 acc[2][8];
  #pragma unroll
  for (int rt = 0; rt < 2; ++rt)
    #pragma unroll
    for (int et = 0; et < 8; ++et) acc[rt][et] = (f32x4){0.f, 0.f, 0.f, 0.f};
  __syncthreads();
  #pragma unroll
  for (int ks = 0; ks < 8; ++ks) {
    f16x8 af[2];
    #pragma unroll
    for (int rt = 0; rt < 2; ++rt)
      af[rt] = *(const f16x8*)(h16 + (size_t)(r0 + w * 32 + rt * 16 + l15) * ND + ks * 32 + kg * 8);
    #pragma unroll
    for (int et = 0; et < 8; ++et) {
      f16x8 bf = *(const f16x8*)&Wl[et * 16 + l15][ks * 32 + kg * 8];
      #pragma unroll
      for (int rt = 0; rt < 2; ++rt)
        acc[rt][et] = __builtin_amdgcn_mfma_f32_16x16x32_f16(af[rt], bf, acc[rt][et], 0, 0, 0);
    }
  }
  #pragma unroll
  for (int rt = 0; rt < 2; ++rt)
    #pragma unroll
    for (int et = 0; et < 8; ++et) {
      const int e = e0 + et * 16 + l15;
      #pragma unroll
      for (int r = 0; r < 4; ++r) {
        const int row = r0 + w * 32 + rt * 16 + kg * 4 + r;
        float v = acc[rt][et][r] + bv[et];
        aw16[(size_t)row * ND + e] = f2h(v > 0.f ? v : 0.f);
      }
    }
}

// ---------------- k2z: Sfrag (raw S) + Z[b][t] = sum_s exp(S). 8 waves, even/odd s split ----------------
__global__ __launch_bounds__(512, 4) void k2z(
    const u16* __restrict__ m16, const u16* __restrict__ aw16,
    u16* __restrict__ Sfrag, float* __restrict__ Zarr)
{
  __shared__ __attribute__((aligned(16))) u16 awch[2][64][264];
  __shared__ float zp[2][64];
  const int tt  = blockIdx.x;        // t-tile of 64 (0..31)
  const int b   = blockIdx.y;
  const int t0  = tt << 6;
  const int tid = threadIdx.x;
  const int lane = tid & 63;
  const int w    = tid >> 6;         // 0..7
  const int grp  = w >> 2;           // s-subchunk half (0: rows 0-31, 1: rows 32-63 of step)
  const int wl   = w & 3;            // t-row owner (16 rows each)
  const int l15 = lane & 15, kg = lane >> 4;
  f16x8 afr[8];
  const size_t abase = ((size_t)(b * NT + t0 + wl * 16 + l15)) * ND + kg * 8;
  #pragma unroll
  for (int ks = 0; ks < 8; ++ks) afr[ks] = *(const f16x8*)(m16 + abase + ks * 32);
  const u16* awb = aw16 + (size_t)b * NT * ND;
  u16* STb = Sfrag + (size_t)b * NT * NT;
  const int ti    = tt * 2 + (wl >> 1);
  const int lanep = l15 + 16 * ((wl & 1) * 2 + (kg >> 1));
  const int jp    = (kg & 1) * 4;
  auto stage = [&](int step, int buf) {     // stage 64 s-rows (s0 = step*64)
    const int s0 = step << 6;
    #pragma unroll
    for (int rep = 0; rep < 4; ++rep) {
      const int idx = rep * 4096 + tid * 8;
      const int srow = idx >> 8, col = idx & 255;
      *(s16x8*)&awch[buf][srow][col] = *(const s16x8*)(awb + (size_t)(s0 + srow) * ND + col);
    }
  };
  stage(0, 0);
  float zacc[4] = {0.f, 0.f, 0.f, 0.f};
  __syncthreads();
  for (int step = 0; step < 32; ++step) {
    const int c = step & 1;
    if (step < 31) stage(step + 1, c ^ 1);
    f32x4 accS[2];
    accS[0] = (f32x4){0.f, 0.f, 0.f, 0.f};
    accS[1] = (f32x4){0.f, 0.f, 0.f, 0.f};
    #pragma unroll
    for (int ks = 0; ks < 8; ++ks) {
      #pragma unroll
      for (int st = 0; st < 2; ++st) {
        f16x8 bf = *(const f16x8*)&awch[c][grp * 32 + st * 16 + l15][ks * 32 + kg * 8];
        accS[st] = __builtin_amdgcn_mfma_f32_16x16x32_f16(afr[ks], bf, accS[st], 0, 0, 0);
      }
    }
    // frag-layout S store + partial Z
    #pragma unroll
    for (int st = 0; st < 2; ++st) {
      const int si = step * 4 + grp * 2 + st;   // s/16 index
      s16x4 sv;
      #pragma unroll
      for (int r = 0; r < 4; ++r) sv[r] = (short)f2h(accS[st][r]);
      *(s16x4*)(STb + (((size_t)si * 64 + ti) * 64 + lanep) * 8 + jp) = sv;
      #pragma unroll
      for (int r = 0; r < 4; ++r) zacc[r] += __expf(accS[st][r]);
    }
    __syncthreads();
  }
  // reduce partial Z over l15, combine the two wave groups via LDS
  #pragma unroll
  for (int r = 0; r < 4; ++r) {
    #pragma unroll
    for (int o = 1; o < 16; o <<= 1) zacc[r] += __shfl_xor(zacc[r], o, 64);
  }
  if (l15 == 0) {
    #pragma unroll
    for (int r = 0; r < 4; ++r) zp[grp][wl * 16 + kg * 4 + r] = zacc[r];
  }
  __syncthreads();
  if (tid < 64)
    Zarr[(size_t)b * NT + t0 + tid] = zp[0][tid] + zp[1][tid];
}

// ---------------- k3o: cooperative exp + PV GEMM. out = h^T + O^T ----------------
__global__ __launch_bounds__(512, 4) void k3o(
    const u16* __restrict__ Sfrag, const u16* __restrict__ hfrag,
    const float* __restrict__ Zarr, float* __restrict__ outp)
{
  __shared__ __attribute__((aligned(16))) u16 Pbuf[2][4][2][64][8];  // [buf][st][ks][lane][8]
  __shared__ float zld[NT];                                          // 1/Z
  const int b   = blockIdx.y;
  const int s0t = blockIdx.x;          // s-tile of 64 (0..31)
  const int tid = threadIdx.x;
  const int lane = tid & 63;
  const int w    = tid >> 6;           // 0..7; owns d-slice [w*32, +32)
  const int l15 = lane & 15, kg = lane >> 4;
  const u16* Sb = Sfrag + (size_t)b * NT * NT;
  const u16* Hb = hfrag + (size_t)b * ND * NT;
  // preload 1/Z (512 threads x 4)
  {
    float4 z = *(const float4*)(Zarr + (size_t)b * NT + tid * 4);
    zld[tid * 4 + 0] = 1.f / z.x;
    zld[tid * 4 + 1] = 1.f / z.y;
    zld[tid * 4 + 2] = 1.f / z.z;
    zld[tid * 4 + 3] = 1.f / z.w;
  }
  const int mst = w >> 1, mks = w & 1;   // this wave's exp duty: sub-frag (st=mst, ks=mks)
  const u16* sp = Sb + ((((size_t)(s0t * 4 + mst)) * 64 + mks) * 64 + lane) * 8;
  auto loadS = [&](int ch) -> s16x8 {
    return *(const s16x8*)(sp + (size_t)ch * 1024);   // ti step 2 per chunk = 1024 u16
  };
  auto expP = [&](s16x8 v, int ch) -> s16x8 {
    const float* rzp = &zld[(ch * 2 + mks) * 32 + kg * 8];
    float4 ra = *(const float4*)rzp;
    float4 rb = *(const float4*)(rzp + 4);
    const float rv[8] = {ra.x, ra.y, ra.z, ra.w, rb.x, rb.y, rb.z, rb.w};
    s16x8 p;
    #pragma unroll
    for (int j = 0; j < 8; ++j) p[j] = (short)f2h(__expf(h2f((u16)v[j])) * rv[j]);
    return p;
  };

  f32x4 acc[4][2];
  #pragma unroll
  for (int st = 0; st < 4; ++st) {
    acc[st][0] = (f32x4){0.f, 0.f, 0.f, 0.f};
    acc[st][1] = (f32x4){0.f, 0.f, 0.f, 0.f};
  }

  s16x8 d0 = loadS(0);
  s16x8 d1 = loadS(1);
  s16x8 d2 = loadS(2);
  __syncthreads();                      // zld ready
  {
    s16x8 pr = expP(d0, 0);
    *(s16x8*)&Pbuf[0][mst][mks][lane][0] = pr;
  }
  __syncthreads();                      // Pbuf[0] ready

  for (int ch = 0; ch < 32; ++ch) {
    const int cur = ch & 1;
    s16x8 prn;
    if (ch < 31) prn = expP(d1, ch + 1);
    d1 = d2;
    if (ch + 3 < 32) d2 = loadS(ch + 3);
    // PV MFMA from Pbuf[cur]
    #pragma unroll
    for (int ks = 0; ks < 2; ++ks) {
      f16x8 pa[4];
      #pragma unroll
      for (int st = 0; st < 4; ++st)
        pa[st] = *(const f16x8*)&Pbuf[cur][st][ks][lane][0];
      #pragma unroll
      for (int dt = 0; dt < 2; ++dt) {
        f16x8 hb = *(const f16x8*)(Hb + (((size_t)(w * 2 + dt) * 64 + ch * 2 + ks) * 64 + lane) * 8);
        #pragma unroll
        for (int st = 0; st < 4; ++st)
          acc[st][dt] = __builtin_amdgcn_mfma_f32_16x16x32_f16(pa[st], hb, acc[st][dt], 0, 0, 0);
      }
    }
    if (ch < 31) *(s16x8*)&Pbuf[cur ^ 1][mst][mks][lane][0] = prn;
    __syncthreads();
  }
  // epilogue: out[b][d][s] = h[d][s] + O[s][d]; residual h from hfrag
  #pragma unroll
  for (int st = 0; st < 4; ++st) {
    const int sb = s0t * 64 + st * 16 + kg * 4;
    #pragma unroll
    for (int dt = 0; dt < 2; ++dt) {
      const int d = w * 32 + dt * 16 + l15;
      const u16* hres = Hb + (((size_t)(w * 2 + dt) * 64 + (s0t * 2 + (st >> 1))) * 64
                        + (l15 + 16 * ((st & 1) * 2 + (kg >> 1)))) * 8 + (kg & 1) * 4;
      float4 o;
      o.x = acc[st][dt][0] + h2f(hres[0]);
      o.y = acc[st][dt][1] + h2f(hres[1]);
      o.z = acc[st][dt][2] + h2f(hres[2]);
      o.w = acc[st][dt][3] + h2f(hres[3]);
      *(float4*)(outp + ((size_t)(b * ND + d)) * NT + sb) = o;
    }
  }
}

extern "C" void kernel_launch(void* const* d_in, const int* in_sizes, int n_in,
                              void* d_out, int out_size, void* d_ws, size_t ws_size,
                              hipStream_t stream) {
  const float* inF  = (const float*)d_in[0];  // [16][2048][512]
  const float* W    = (const float*)d_in[1];  // [256][256]
  const float* bias = (const float*)d_in[2];  // [256]
  float* outp = (float*)d_out;                // [16][256][2048]

  const size_t SZ = (size_t)NB * NT * ND;     // 8,388,608 elems
  u16* m16   = (u16*)d_ws;
  u16* hfrag = m16 + SZ;
  u16* aw16  = hfrag + SZ;
  float* Zarr = (float*)(aw16 + SZ);          // [B][NT] fp32 Z
  u16* Sfrag = (u16*)(Zarr + (size_t)NB * NT); // fp16 fragment-tiled S, 128 MiB
  u16* h16   = Sfrag;                          // alias: dead after kB, overwritten by k2z
  const size_t need = 3 * SZ * sizeof(u16) + (size_t)NB * NT * sizeof(float)
                    + (size_t)NB * NT * NT * sizeof(u16);   // identical to r6's proven size
  if (ws_size < need) return;  // visible failure (output stays poisoned)

  kA <<<dim3(NB * NT / 64), dim3(256), 0, stream>>>(inF, h16, m16, hfrag);
  kB <<<dim3(256, 2), dim3(256), 0, stream>>>(h16, W, bias, aw16);
  k2z<<<dim3(32, NB), dim3(512), 0, stream>>>(m16, aw16, Sfrag, Zarr);
  k3o<<<dim3(NT / 64, NB), dim3(512), 0, stream>>>(Sfrag, hfrag, Zarr, outp);
}